// Round 7
// baseline (254.044 us; speedup 1.0000x reference)
//
#include <hip/hip_runtime.h>
#include <math.h>

#define BB  2
#define TT  2048
#define SSQ 2048
#define DD  1024
#define HH  16
#define DKK 64
#define MM  (BB*TT)      // 4096 rows of activations
#define NN  (HH*DKK)     // 1024 proj width

typedef __attribute__((ext_vector_type(8))) short short8;
typedef __attribute__((ext_vector_type(4))) float f32x4;

__device__ __forceinline__ short f2bf(float x) {
    unsigned u = __builtin_bit_cast(unsigned, x);
    unsigned r = (u + 0x7FFFu + ((u >> 16) & 1u)) >> 16;
    return (short)r;
}

__device__ __forceinline__ void glds16(const void* g, void* l) {
    __builtin_amdgcn_global_load_lds(
        (const __attribute__((address_space(1))) void*)g,
        (__attribute__((address_space(3))) void*)l, 16, 0, 0);
}

// ---------------------------------------------------------------------------
// fp32 -> bf16 elementwise (query/key/value), grid (MM*DD/2048, 3)
// ---------------------------------------------------------------------------
__global__ __launch_bounds__(256)
void to_bf16_acts(const float* __restrict__ a0, const float* __restrict__ a1,
                  const float* __restrict__ a2,
                  short* __restrict__ o0, short* __restrict__ o1,
                  short* __restrict__ o2)
{
    int z = blockIdx.y;
    const float* in = (z == 0) ? a0 : (z == 1) ? a1 : a2;
    short* out = (z == 0) ? o0 : (z == 1) ? o1 : o2;
    size_t i0 = ((size_t)blockIdx.x * 256 + threadIdx.x) * 8;
    f32x4 f0 = *(const f32x4*)(in + i0);
    f32x4 f1 = *(const f32x4*)(in + i0 + 4);
    short8 v;
#pragma unroll
    for (int j = 0; j < 4; j++) v[j] = f2bf(f0[j]);
#pragma unroll
    for (int j = 0; j < 4; j++) v[4 + j] = f2bf(f1[j]);
    *(short8*)(out + i0) = v;
}

// ---------------------------------------------------------------------------
// Weight transpose+convert: fp32 [K=1024][N=1024] -> bf16 [N][K].
// grid (16,16,4): z picks which weight.
// ---------------------------------------------------------------------------
__global__ __launch_bounds__(256)
void wtrans(const float* __restrict__ w0, const float* __restrict__ w1,
            const float* __restrict__ w2, const float* __restrict__ w3,
            short* __restrict__ t0, short* __restrict__ t1,
            short* __restrict__ t2, short* __restrict__ t3)
{
    __shared__ float Ls[64][65];
    int z = blockIdx.z;
    const float* in = (z == 0) ? w0 : (z == 1) ? w1 : (z == 2) ? w2 : w3;
    short* out = (z == 0) ? t0 : (z == 1) ? t1 : (z == 2) ? t2 : t3;
    const int r0 = blockIdx.y * 64, c0 = blockIdx.x * 64;
    const int t = threadIdx.x;
    const int r = t >> 2, c4 = t & 3;

    const float* src = in + (size_t)(r0 + r) * DD + c0 + c4 * 16;
#pragma unroll
    for (int i = 0; i < 4; i++) {
        f32x4 f = *(const f32x4*)(src + i * 4);
#pragma unroll
        for (int j = 0; j < 4; j++) Ls[r][c4 * 16 + i * 4 + j] = f[j];
    }
    __syncthreads();

    short8 va, vb;
#pragma unroll
    for (int j = 0; j < 8; j++) va[j] = f2bf(Ls[c4 * 16 + j][r]);
#pragma unroll
    for (int j = 0; j < 8; j++) vb[j] = f2bf(Ls[c4 * 16 + 8 + j][r]);
    short* dst = out + (size_t)(c0 + r) * DD + r0 + c4 * 16;
    *(short8*)dst = va;
    *(short8*)(dst + 8) = vb;
}

// ---------------------------------------------------------------------------
// bf16 transpose: [bh][t][dk=64] -> [bh][dk][t]. grid (TT/64, BB*HH).
// ---------------------------------------------------------------------------
__global__ __launch_bounds__(256)
void vtrans(const short* __restrict__ in, short* __restrict__ out)
{
    __shared__ short Ls[64][72];
    const int bh = blockIdx.y;
    const int t0 = blockIdx.x * 64;
    const int tid = threadIdx.x;
    const int r = tid >> 2, c4 = tid & 3;

    const short* src = in + ((size_t)bh * TT + t0 + r) * DKK + c4 * 16;
    *(short8*)&Ls[r][c4 * 16]     = *(const short8*)(src);
    *(short8*)&Ls[r][c4 * 16 + 8] = *(const short8*)(src + 8);
    __syncthreads();

    short8 a, b;
#pragma unroll
    for (int j = 0; j < 8; j++) a[j] = Ls[c4 * 16 + j][r];
#pragma unroll
    for (int j = 0; j < 8; j++) b[j] = Ls[c4 * 16 + 8 + j][r];
    short* dst = out + ((size_t)bh * DKK + r) * SSQ + t0 + c4 * 16;
    *(short8*)dst = a;
    *(short8*)(dst + 8) = b;
}

// ---------------------------------------------------------------------------
// m97-style bf16 GEMM core: C128x128 = A[M][K] @ Bt[N][K]^T, BK=32,
// 256 thr = 4 waves (2x2), each wave 64x64 = 4x4 MFMA tiles.
// ---------------------------------------------------------------------------
__device__ __forceinline__ void gemm_core(const short* __restrict__ A,
                                          const short* __restrict__ Bt,
                                          int m0, int n0,
                                          short* As, short* Bs,
                                          f32x4 (&acc)[4][4])
{
    const int tid = threadIdx.x;
    const int w = tid >> 6, l = tid & 63;
    const int l15 = l & 15, quad = l >> 4;
    const int wm = w >> 1, wn = w & 1;

#pragma unroll
    for (int i = 0; i < 4; i++)
#pragma unroll
        for (int j = 0; j < 4; j++) acc[i][j] = (f32x4){0.f, 0.f, 0.f, 0.f};

    const int r = tid >> 2, cseg = tid & 3;
    const short* gA = A + (size_t)(m0 + r) * DD + cseg * 8;
    const short* gB = Bt + (size_t)(n0 + r) * DD + cseg * 8;
    short* ldsA = As + w * 512;
    short* ldsB = Bs + w * 512;

    for (int k0 = 0; k0 < DD; k0 += 32) {
        glds16(gA + k0,                 ldsA);
        glds16(gA + (size_t)64 * DD + k0, ldsA + 2048);
        glds16(gB + k0,                 ldsB);
        glds16(gB + (size_t)64 * DD + k0, ldsB + 2048);
        __syncthreads();

        short8 bF[4];
#pragma unroll
        for (int ni = 0; ni < 4; ni++)
            bF[ni] = *(const short8*)&Bs[(wn * 64 + ni * 16 + l15) * 32 + quad * 8];
#pragma unroll
        for (int mi = 0; mi < 4; mi++) {
            short8 aF = *(const short8*)&As[(wm * 64 + mi * 16 + l15) * 32 + quad * 8];
#pragma unroll
            for (int ni = 0; ni < 4; ni++)
                acc[mi][ni] = __builtin_amdgcn_mfma_f32_16x16x32_bf16(aF, bF[ni], acc[mi][ni], 0, 0, 0);
        }
        __syncthreads();
    }
}

// ---------------------------------------------------------------------------
// QKV projection GEMM. z picks {Q,K,V}. All outputs bf16 [bh][t][dk]
// (coalesced stores); V transposed later by vtrans.
// Q scaled by 1/sqrt(dk)*log2(e) so attention uses exp2.
// ---------------------------------------------------------------------------
__global__ __launch_bounds__(256, 3)
void gemm_qkv(const short* __restrict__ Aq, const short* __restrict__ Ak,
              const short* __restrict__ Av,
              const short* __restrict__ Wqt, const short* __restrict__ Wkt,
              const short* __restrict__ Wvt,
              const float* __restrict__ bq, const float* __restrict__ bk,
              const float* __restrict__ bv,
              short* __restrict__ Qb, short* __restrict__ Kb,
              short* __restrict__ Vtmp)
{
    __shared__ short As[128 * 32];
    __shared__ short Bs[128 * 32];
    const int z = blockIdx.z;
    const short* A  = (z == 0) ? Aq : (z == 1) ? Ak : Av;
    const short* Bt = (z == 0) ? Wqt : (z == 1) ? Wkt : Wvt;
    const float* bias = (z == 0) ? bq : (z == 1) ? bk : bv;
    short* dst = (z == 0) ? Qb : (z == 1) ? Kb : Vtmp;
    const int m0 = blockIdx.y * 128, n0 = blockIdx.x * 128;

    f32x4 acc[4][4];
    gemm_core(A, Bt, m0, n0, As, Bs, acc);

    const int tid = threadIdx.x;
    const int w = tid >> 6, l = tid & 63;
    const int l15 = l & 15, quad = l >> 4;
    const int wm = w >> 1, wn = w & 1;
    const float scale = (z == 0) ? 0.1803368801f : 1.0f;

#pragma unroll
    for (int mi = 0; mi < 4; mi++) {
#pragma unroll
        for (int reg = 0; reg < 4; reg++) {
            int m = m0 + wm * 64 + mi * 16 + quad * 4 + reg;
            int b = m >> 11, t = m & 2047;
#pragma unroll
            for (int ni = 0; ni < 4; ni++) {
                int n = n0 + wn * 64 + ni * 16 + l15;
                float vv = (acc[mi][ni][reg] + bias[n]) * scale;
                int h = n >> 6, dk = n & 63;
                dst[((size_t)(b * HH + h) * TT + t) * DKK + dk] = f2bf(vv);
            }
        }
    }
}

// ---------------------------------------------------------------------------
// Output projection GEMM: out[M][D] = Ab @ Wot^T + bo, fp32 out.
// Tile 128(m) x 64(n): grid (16,32)=512 blocks -> 2 blocks/CU (vs 1 at 128x128)
// 4 waves stacked on m: wave w = rows [32w,32w+32) x all 64 n.
// ---------------------------------------------------------------------------
__global__ __launch_bounds__(256, 2)
void gemm_out(const short* __restrict__ Ab, const short* __restrict__ Wot,
              const float* __restrict__ bo, float* __restrict__ out)
{
    __shared__ short As[128 * 32];
    __shared__ short Bs[64 * 32];
    const int m0 = blockIdx.y * 128, n0 = blockIdx.x * 64;
    const int tid = threadIdx.x;
    const int w = tid >> 6, l = tid & 63;
    const int l15 = l & 15, quad = l >> 4;

    f32x4 acc[2][4];
#pragma unroll
    for (int i = 0; i < 2; i++)
#pragma unroll
        for (int j = 0; j < 4; j++) acc[i][j] = (f32x4){0.f, 0.f, 0.f, 0.f};

    const int r = tid >> 2, cseg = tid & 3;
    const short* gA = Ab + (size_t)(m0 + r) * DD + cseg * 8;
    const short* gB = Wot + (size_t)(n0 + r) * DD + cseg * 8;
    short* ldsA = As + w * 512;
    short* ldsB = Bs + w * 512;

    for (int k0 = 0; k0 < DD; k0 += 32) {
        glds16(gA + k0,                   ldsA);
        glds16(gA + (size_t)64 * DD + k0, ldsA + 2048);
        glds16(gB + k0,                   ldsB);   // B tile 64x32 = one glds
        __syncthreads();

        short8 bF[4];
#pragma unroll
        for (int ni = 0; ni < 4; ni++)
            bF[ni] = *(const short8*)&Bs[(ni * 16 + l15) * 32 + quad * 8];
#pragma unroll
        for (int mi = 0; mi < 2; mi++) {
            short8 aF = *(const short8*)&As[(w * 32 + mi * 16 + l15) * 32 + quad * 8];
#pragma unroll
            for (int ni = 0; ni < 4; ni++)
                acc[mi][ni] = __builtin_amdgcn_mfma_f32_16x16x32_bf16(aF, bF[ni], acc[mi][ni], 0, 0, 0);
        }
        __syncthreads();
    }

#pragma unroll
    for (int mi = 0; mi < 2; mi++) {
#pragma unroll
        for (int reg = 0; reg < 4; reg++) {
            int m = m0 + w * 32 + mi * 16 + quad * 4 + reg;
#pragma unroll
            for (int ni = 0; ni < 4; ni++) {
                int n = n0 + ni * 16 + l15;
                out[(size_t)m * DD + n] = acc[mi][ni][reg] + bo[n];
            }
        }
    }
}

// ---------------------------------------------------------------------------
// bf16 MFMA flash attention. BT=128 (4 waves x 32 q-rows), BS=128 staged
// tiles computed in two s-halves -> half the barriers of BS=64.
// LDS strides 68/132 (bank-starts 2*l15+4*quad: <=4-way on b128 frags,
// P-writes conflict-free). No-max softmax (exp2, log2e folded into Q).
// K/V register-prefetched across tiles. Q staging & P are wave-local.
// ---------------------------------------------------------------------------
__global__ __launch_bounds__(256, 2)
void attn_mfma(const short* __restrict__ Qb, const short* __restrict__ Kb,
               const short* __restrict__ Vbt, short* __restrict__ Ab)
{
    __shared__ short QPs[128 * 132];  // Q staging (64 cols), then P (128 cols)
    __shared__ short Ks[128 * 68];    // [s][dk]
    __shared__ short Vs[64 * 132];    // [dk][s]

    const int tid = threadIdx.x;
    const int w = tid >> 6, l = tid & 63;
    const int l15 = l & 15, quad = l >> 4;
    const int bh = blockIdx.y;
    const int t0 = blockIdx.x * 128;
    const size_t hb = (size_t)bh * SSQ * DKK;

    // ---- stage Q tile 128x64 (wave-local rows: tid>>1 in [32w,32w+32)) ----
    {
        int r2 = tid >> 1, half = tid & 1;
        const short* g = Qb + hb + (size_t)(t0 + r2) * 64 + half * 32;
        short* s = QPs + r2 * 132 + half * 32;
        *(short8*)(s + 0)  = *(const short8*)(g + 0);
        *(short8*)(s + 8)  = *(const short8*)(g + 8);
        *(short8*)(s + 16) = *(const short8*)(g + 16);
        *(short8*)(s + 24) = *(const short8*)(g + 24);
    }
    __threadfence_block();
    short8 qf[2][2];
#pragma unroll
    for (int mf = 0; mf < 2; mf++)
#pragma unroll
        for (int kk = 0; kk < 2; kk++)
            qf[mf][kk] = *(const short8*)&QPs[(32 * w + 16 * mf + l15) * 132 + kk * 32 + quad * 8];

    // ---- staging geometry: K rows 0..127 (2 thr/row), V rows 0..63 (4/row) --
    const int rk = tid >> 1, kseg = (tid & 1) * 32;
    const int rv = tid >> 2, vseg = (tid & 3) * 32;
    const short* gkb = Kb + hb + (size_t)rk * 64 + kseg;    // + s0*64
    const short* gvb = Vbt + hb + (size_t)rv * SSQ + vseg;  // + s0
    short* sk = Ks + rk * 68 + kseg;
    short* sv = Vs + rv * 132 + vseg;

    // ---- prefetch tile 0 ----
    short8 kr[4], vr[4];
#pragma unroll
    for (int i = 0; i < 4; i++) {
        kr[i] = *(const short8*)(gkb + i * 8);
        vr[i] = *(const short8*)(gvb + i * 8);
    }

    f32x4 o[2][4];
#pragma unroll
    for (int mf = 0; mf < 2; mf++)
#pragma unroll
        for (int j = 0; j < 4; j++) o[mf][j] = (f32x4){0.f, 0.f, 0.f, 0.f};
    float lsum[2][4];
#pragma unroll
    for (int mf = 0; mf < 2; mf++)
#pragma unroll
        for (int j = 0; j < 4; j++) lsum[mf][j] = 0.f;

    for (int s0 = 0; s0 < SSQ; s0 += 128) {
        __syncthreads();            // prev PV done reading Ks/Vs
#pragma unroll
        for (int i = 0; i < 4; i++) {
            *(short8*)(sk + i * 8) = kr[i];
            *(short8*)(sv + i * 8) = vr[i];
        }
        if (s0 + 128 < SSQ) {
            const short* gk = gkb + (size_t)(s0 + 128) * 64;
            const short* gv = gvb + (s0 + 128);
#pragma unroll
            for (int i = 0; i < 4; i++) {
                kr[i] = *(const short8*)(gk + i * 8);
                vr[i] = *(const short8*)(gv + i * 8);
            }
        }
        __syncthreads();            // K/V tiles visible to all waves

        // ---- S = Q K^T + exp2, two s-halves of 64 ----
#pragma unroll
        for (int sh = 0; sh < 2; sh++) {
            f32x4 sc[2][4];
#pragma unroll
            for (int mf = 0; mf < 2; mf++)
#pragma unroll
                for (int j = 0; j < 4; j++) sc[mf][j] = (f32x4){0.f, 0.f, 0.f, 0.f};
#pragma unroll
            for (int kk = 0; kk < 2; kk++) {
#pragma unroll
                for (int np = 0; np < 4; np++) {
                    short8 bK = *(const short8*)&Ks[(sh * 64 + 16 * np + l15) * 68 + kk * 32 + quad * 8];
                    sc[0][np] = __builtin_amdgcn_mfma_f32_16x16x32_bf16(qf[0][kk], bK, sc[0][np], 0, 0, 0);
                    sc[1][np] = __builtin_amdgcn_mfma_f32_16x16x32_bf16(qf[1][kk], bK, sc[1][np], 0, 0, 0);
                }
            }
#pragma unroll
            for (int mf = 0; mf < 2; mf++) {
                int prow = (32 * w + 16 * mf + quad * 4) * 132 + sh * 64 + l15;
#pragma unroll
                for (int reg = 0; reg < 4; reg++) {
                    int pr = prow + reg * 132;
#pragma unroll
                    for (int np = 0; np < 4; np++) {
                        float p = __builtin_amdgcn_exp2f(sc[mf][np][reg]);
                        QPs[pr + 16 * np] = (short)(__builtin_bit_cast(unsigned, p) >> 16);
                        lsum[mf][reg] += p;
                    }
                }
            }
        }
        __threadfence_block();      // wave-local P visibility

        // ---- O += P V over full s=128 (4 kk) ----
#pragma unroll
        for (int kk = 0; kk < 4; kk++) {
            short8 aP0 = *(const short8*)&QPs[(32 * w + l15) * 132 + kk * 32 + quad * 8];
            short8 aP1 = *(const short8*)&QPs[(32 * w + 16 + l15) * 132 + kk * 32 + quad * 8];
#pragma unroll
            for (int nf = 0; nf < 4; nf++) {
                short8 bV = *(const short8*)&Vs[(16 * nf + l15) * 132 + kk * 32 + quad * 8];
                o[0][nf] = __builtin_amdgcn_mfma_f32_16x16x32_bf16(aP0, bV, o[0][nf], 0, 0, 0);
                o[1][nf] = __builtin_amdgcn_mfma_f32_16x16x32_bf16(aP1, bV, o[1][nf], 0, 0, 0);
            }
        }
    }

    // ---- epilogue: single l-reduction, write bf16 Ab[b][t][h][dk] ----
    const int b = bh >> 4, h = bh & 15;
#pragma unroll
    for (int mf = 0; mf < 2; mf++) {
#pragma unroll
        for (int reg = 0; reg < 4; reg++) {
            float ls = lsum[mf][reg];
            ls += __shfl_xor(ls, 1);
            ls += __shfl_xor(ls, 2);
            ls += __shfl_xor(ls, 4);
            ls += __shfl_xor(ls, 8);
            float inv = 1.f / ls;
            int t = t0 + 32 * w + 16 * mf + quad * 4 + reg;
#pragma unroll
            for (int nf = 0; nf < 4; nf++) {
                Ab[((size_t)(b * TT + t) * HH + h) * DKK + 16 * nf + l15] =
                    f2bf(o[mf][nf][reg] * inv);
            }
        }
    }
}

// ---------------------------------------------------------------------------
extern "C" void kernel_launch(void* const* d_in, const int* in_sizes, int n_in,
                              void* d_out, int out_size, void* d_ws, size_t ws_size,
                              hipStream_t stream)
{
    const float* query = (const float*)d_in[0];
    const float* value = (const float*)d_in[1];
    const float* key   = (const float*)d_in[2];
    const float* Wq    = (const float*)d_in[3];
    const float* bq    = (const float*)d_in[4];
    const float* Wk    = (const float*)d_in[5];
    const float* bk    = (const float*)d_in[6];
    const float* Wv    = (const float*)d_in[7];
    const float* bv    = (const float*)d_in[8];
    const float* Wo    = (const float*)d_in[9];
    const float* bo    = (const float*)d_in[10];
    float* out = (float*)d_out;

    const size_t actE = (size_t)MM * DD;    // 4.19M elems
    const size_t wE   = (size_t)DD * NN;    // 1.05M elems
    short* p = (short*)d_ws;
    short* Aq   = p; p += actE;
    short* Ak   = p; p += actE;
    short* Av   = p; p += actE;
    short* Wqt  = p; p += wE;
    short* Wkt  = p; p += wE;
    short* Wvt  = p; p += wE;
    short* Wot  = p; p += wE;
    short* Qb   = p; p += actE;
    short* Kb   = p; p += actE;
    short* Vtmp = p; p += actE;
    short* Vbt  = p; p += actE;
    short* Ab   = p; p += actE;

    dim3 blk(256);

    // 1. activations fp32 -> bf16
    to_bf16_acts<<<dim3((unsigned)(actE / 2048), 3), blk, 0, stream>>>(
        query, key, value, Aq, Ak, Av);

    // 2. weights fp32 [K][N] -> bf16 [N][K]
    wtrans<<<dim3(16, 16, 4), blk, 0, stream>>>(Wq, Wk, Wv, Wo, Wqt, Wkt, Wvt, Wot);

    // 3. fused QKV projections; all outputs bf16 [bh][t][dk]
    gemm_qkv<<<dim3(NN / 128, MM / 128, 3), blk, 0, stream>>>(
        Aq, Ak, Av, Wqt, Wkt, Wvt, bq, bk, bv, Qb, Kb, Vtmp);

    // 4. V transpose -> [bh][dk][s]
    vtrans<<<dim3(TT / 64, BB * HH), blk, 0, stream>>>(Vtmp, Vbt);

    // 5. flash attention -> bf16 Ab [m][h*64+dk]
    attn_mfma<<<dim3(TT / 128, BB * HH), blk, 0, stream>>>(Qb, Kb, Vbt, Ab);

    // 6. output projection -> fp32 out (128x64 tiles, 512 blocks = 2/CU)
    gemm_out<<<dim3(DD / 64, MM / 128), blk, 0, stream>>>(Ab, Wot, bo, out);
}